// Round 7
// baseline (241.463 us; speedup 1.0000x reference)
//
#include <hip/hip_runtime.h>
#include <hip/hip_bf16.h>
#include <math.h>

#define SS 2048
#define HH 1024
#define NHH 16
#define HDD 64
#define BH 32
#define MM 4096

typedef unsigned short u16;
using bf16x8 = __attribute__((ext_vector_type(8))) short;
using floatx4 = __attribute__((ext_vector_type(4))) float;

__device__ __forceinline__ u16 f2bf(float f) {
  unsigned u = __float_as_uint(f);
  u += 0x7fffu + ((u >> 16) & 1u);
  return (u16)(u >> 16);
}
__device__ __forceinline__ unsigned pk_bf16(float a, float b) {
  union { __hip_bfloat162 h2; unsigned u; } c;
  c.h2 = __float22bfloat162_rn(float2{a, b});
  return c.u;
}
__device__ __forceinline__ void gload_lds16(const u16* g, u16* l) {
  __builtin_amdgcn_global_load_lds(
      (const __attribute__((address_space(1))) void*)g,
      (__attribute__((address_space(3))) void*)l, 16, 0, 0);
}

// ---------------------------------------------------------------------------
// fp32 -> bf16 conversion (hs + 4 weights) + RoPE cos/sin table.
// ---------------------------------------------------------------------------
__global__ __launch_bounds__(256) void convert_bf(
    const float* __restrict__ hs, const float* __restrict__ wq,
    const float* __restrict__ wk, const float* __restrict__ wv,
    const float* __restrict__ wo, const int* __restrict__ pos,
    u16* __restrict__ hs_b, u16* __restrict__ wq_b, u16* __restrict__ wk_b,
    u16* __restrict__ wv_b, u16* __restrict__ wo_b,
    float2* __restrict__ tab) {
  int g = blockIdx.x * 256 + threadIdx.x;
  if (g < 2097152) {
    const float* src;
    u16* dst;
    int off;
    if (g < 1048576) {
      src = hs; dst = hs_b; off = g;
    } else {
      int t = g - 1048576;
      int w = t >> 18;
      off = t & 262143;
      src = (w == 0) ? wq : (w == 1) ? wk : (w == 2) ? wv : wo;
      dst = (w == 0) ? wq_b : (w == 1) ? wk_b : (w == 2) ? wv_b : wo_b;
    }
    float4 v = ((const float4*)src)[off];
    ushort4 o = make_ushort4(f2bf(v.x), f2bf(v.y), f2bf(v.z), f2bf(v.w));
    ((ushort4*)dst)[off] = o;
  } else {
    int idx = g - 2097152;  // 0..65535
    int s = idx >> 5, j = idx & 31;
    float p = (float)pos[s];
    const float c0 = 13.287712379549449f / 32.0f;  // log2(10000)/32
    float f = p * exp2f(-(float)j * c0);
    float sn, cs;
    sincosf(f, &sn, &cs);
    tab[idx] = float2{cs, sn};
  }
}

// ---------------------------------------------------------------------------
// QKV MFMA GEMM: 128x128 tile, BK=32, global_load_lds w16, XOR swizzle.
// grid.x spans Wq|Wk|Wv; Q/K get table RoPE in the epilogue (Q pre-scaled by
// (1/sqrt(HD))*log2e), bf16 head-major out; V written transposed Vt[bh][d][s].
// ---------------------------------------------------------------------------
__global__ __launch_bounds__(256) void mfma_gemm_qkv(
    const u16* __restrict__ X, const u16* __restrict__ W0,
    const u16* __restrict__ W1, const u16* __restrict__ W2,
    const float* __restrict__ b0, const float* __restrict__ b1,
    const float* __restrict__ b2, const float2* __restrict__ tab,
    u16* __restrict__ O0, u16* __restrict__ O1, u16* __restrict__ O2) {
  __shared__ __align__(16) u16 As[128 * 32];
  __shared__ __align__(16) u16 Bs[128 * 32];
  const int tid = threadIdx.x;
  const int lane = tid & 63;
  const int wvu = __builtin_amdgcn_readfirstlane(tid >> 6);
  const int l15 = lane & 15;
  const int quad = lane >> 4;
  const int wm = wvu >> 1, wn = wvu & 1;
  const int m0 = blockIdx.y * 128;
  const int n0g = blockIdx.x * 128;
  const int lr = lane >> 2;
  const int lc = lane & 3;

  int wsel = n0g >> 10;
  int n0 = n0g & 1023;
  const u16* Wsel = (wsel == 1) ? W1 : (wsel == 2) ? W2 : W0;
  const float* bsel = (wsel == 1) ? b1 : (wsel == 2) ? b2 : b0;
  u16* Osel = (wsel == 1) ? O1 : (wsel == 2) ? O2 : O0;

  floatx4 acc[4][4];
#pragma unroll
  for (int i = 0; i < 4; ++i)
#pragma unroll
    for (int j = 0; j < 4; ++j) acc[i][j] = (floatx4){0.f, 0.f, 0.f, 0.f};

  const int scol = (lc ^ ((lr >> 1) & 3)) * 8;
  const int fsw = ((l15 >> 1) & 3);

  for (int k0 = 0; k0 < HH; k0 += 32) {
#pragma unroll
    for (int u = 0; u < 2; ++u) {
      int r = u * 64 + wvu * 16 + lr;
      gload_lds16(&X[(size_t)(m0 + r) * HH + k0 + scol],
                  &As[(u * 64 + wvu * 16) * 32]);
      gload_lds16(&Wsel[(size_t)(n0 + r) * HH + k0 + scol],
                  &Bs[(u * 64 + wvu * 16) * 32]);
    }
    __syncthreads();
    bf16x8 af[4], bfr[4];
#pragma unroll
    for (int mb = 0; mb < 4; ++mb)
      af[mb] = *(const bf16x8*)&As[(wm * 64 + mb * 16 + l15) * 32 +
                                   ((quad ^ fsw) * 8)];
#pragma unroll
    for (int nb = 0; nb < 4; ++nb)
      bfr[nb] = *(const bf16x8*)&Bs[(wn * 64 + nb * 16 + l15) * 32 +
                                    ((quad ^ fsw) * 8)];
#pragma unroll
    for (int mb = 0; mb < 4; ++mb)
#pragma unroll
      for (int nb = 0; nb < 4; ++nb)
        acc[mb][nb] = __builtin_amdgcn_mfma_f32_16x16x32_bf16(
            af[mb], bfr[nb], acc[mb][nb], 0, 0, 0);
    __syncthreads();
  }

  if (wsel < 2) {
    const float qs = (wsel == 0) ? 0.125f * 1.44269504088896f : 1.0f;
    const int colb = n0 + wn * 64;
    const int h = colb >> 6;
    const float bias0 = bsel[colb + l15];
    const float bias1 = bsel[colb + 16 + l15];
    const float bias2 = bsel[colb + 32 + l15];
    const float bias3 = bsel[colb + 48 + l15];
#pragma unroll
    for (int mb = 0; mb < 4; ++mb)
#pragma unroll
      for (int r = 0; r < 4; ++r) {
        int m = m0 + wm * 64 + mb * 16 + quad * 4 + r;
        int b = m >> 11, s = m & (SS - 1);
        float2 t0 = tab[s * 32 + l15];
        float2 t1 = tab[s * 32 + 16 + l15];
        size_t obase = ((size_t)(b * NHH + h) * SS + s) * HDD;
        float x1 = acc[mb][0][r] + bias0;
        float x2 = acc[mb][2][r] + bias2;
        Osel[obase + l15] = f2bf((x1 * t0.x - x2 * t0.y) * qs);
        Osel[obase + 32 + l15] = f2bf((x2 * t0.x + x1 * t0.y) * qs);
        float y1 = acc[mb][1][r] + bias1;
        float y2 = acc[mb][3][r] + bias3;
        Osel[obase + 16 + l15] = f2bf((y1 * t1.x - y2 * t1.y) * qs);
        Osel[obase + 48 + l15] = f2bf((y2 * t1.x + y1 * t1.y) * qs);
      }
  } else {
#pragma unroll
    for (int nb = 0; nb < 4; ++nb) {
      int col = n0 + wn * 64 + nb * 16 + l15;
      int h = col >> 6, d = col & 63;
      float bias = bsel[col];
#pragma unroll
      for (int mb = 0; mb < 4; ++mb) {
        int m = m0 + wm * 64 + mb * 16 + quad * 4;
        int b = m >> 11, s = m & (SS - 1);
        uint2 w2;
        w2.x = pk_bf16(acc[mb][nb][0] + bias, acc[mb][nb][1] + bias);
        w2.y = pk_bf16(acc[mb][nb][2] + bias, acc[mb][nb][3] + bias);
        *(uint2*)&Osel[((size_t)((b * NHH + h) * HDD + d)) * SS + s] = w2;
      }
    }
  }
}

// ---------------------------------------------------------------------------
// Final projection GEMM: 128(m) x 64(n) tiles -> 512 blocks. fp32 out.
// ---------------------------------------------------------------------------
__global__ __launch_bounds__(256) void gemm_out(const u16* __restrict__ X,
                                                const u16* __restrict__ W,
                                                float* __restrict__ Ofp) {
  __shared__ __align__(16) u16 As[128 * 32];
  __shared__ __align__(16) u16 Bs[64 * 32];
  const int tid = threadIdx.x;
  const int lane = tid & 63;
  const int wvu = __builtin_amdgcn_readfirstlane(tid >> 6);
  const int l15 = lane & 15;
  const int quad = lane >> 4;
  const int wm = wvu >> 1, wn = wvu & 1;
  const int m0 = blockIdx.y * 128;
  const int n0 = blockIdx.x * 64;
  const int lr = lane >> 2;
  const int lc = lane & 3;

  floatx4 acc[4][2];
#pragma unroll
  for (int i = 0; i < 4; ++i)
#pragma unroll
    for (int j = 0; j < 2; ++j) acc[i][j] = (floatx4){0.f, 0.f, 0.f, 0.f};

  const int scol = (lc ^ ((lr >> 1) & 3)) * 8;
  const int fsw = ((l15 >> 1) & 3);

  for (int k0 = 0; k0 < HH; k0 += 32) {
#pragma unroll
    for (int u = 0; u < 2; ++u) {
      int r = u * 64 + wvu * 16 + lr;
      gload_lds16(&X[(size_t)(m0 + r) * HH + k0 + scol],
                  &As[(u * 64 + wvu * 16) * 32]);
    }
    gload_lds16(&W[(size_t)(n0 + wvu * 16 + lr) * HH + k0 + scol],
                &Bs[(wvu * 16) * 32]);
    __syncthreads();
    bf16x8 af[4], bfr[2];
#pragma unroll
    for (int mb = 0; mb < 4; ++mb)
      af[mb] = *(const bf16x8*)&As[(wm * 64 + mb * 16 + l15) * 32 +
                                   ((quad ^ fsw) * 8)];
#pragma unroll
    for (int nb = 0; nb < 2; ++nb)
      bfr[nb] = *(const bf16x8*)&Bs[(wn * 32 + nb * 16 + l15) * 32 +
                                    ((quad ^ fsw) * 8)];
#pragma unroll
    for (int mb = 0; mb < 4; ++mb)
#pragma unroll
      for (int nb = 0; nb < 2; ++nb)
        acc[mb][nb] = __builtin_amdgcn_mfma_f32_16x16x32_bf16(
            af[mb], bfr[nb], acc[mb][nb], 0, 0, 0);
    __syncthreads();
  }

#pragma unroll
  for (int mb = 0; mb < 4; ++mb)
#pragma unroll
    for (int r = 0; r < 4; ++r) {
      int m = m0 + wm * 64 + mb * 16 + quad * 4 + r;
#pragma unroll
      for (int nb = 0; nb < 2; ++nb)
        Ofp[(size_t)m * HH + n0 + wn * 32 + nb * 16 + l15] = acc[mb][nb][r];
    }
}

// ---------------------------------------------------------------------------
// Flash attention, BARRIER-FREE K-loop. Wave (kh,qh) owns keys kh*32..+31 x
// qrows qh*32..+31 of a 64-qrow block. Q and K frags are loaded DIRECTLY from
// global into registers (frag layout is 16B-contiguous in [s][d]); K(t+1) is
// prefetched mid-tile (register vmcnt pipelining by the compiler). V^T lives
// in wave-PRIVATE LDS quadrants (4 KB/wave, double-buffered, chunk-XOR per
// d-row), staged by global_load_lds; correctness needs only s_waitcnt(0) at
// tile top (own loads, issued a full tile earlier). NO __syncthreads in the
// loop. PV uses the in-register permuted-P trick (P never leaves registers).
// Epilogue: 2 barriers to combine the kh halves via LDS.
// ---------------------------------------------------------------------------
__global__ __launch_bounds__(256, 3) void attn_mfma(const u16* __restrict__ Qg,
                                                    const u16* __restrict__ Kg,
                                                    const u16* __restrict__ Vtg,
                                                    u16* __restrict__ A) {
  __shared__ __align__(16) u16 smem[16384];  // 32 KB: 2 bufs x 4 waves x 4 KB
  const int tid = threadIdx.x;
  const int lane = tid & 63;
  const int wv = __builtin_amdgcn_readfirstlane(tid >> 6);
  const int l15 = lane & 15, quad = lane >> 4;
  const int qt = blockIdx.x, bh = blockIdx.y;
  const size_t hb = (size_t)bh * SS * HDD;  // Q,K [bh][s][d]; Vt [bh][d][s]
  const int kh = wv >> 1, qh = wv & 1;

  u16* const vbuf0 = smem + wv * 2048;
  u16* const vbuf1 = smem + 8192 + wv * 2048;

  // V staging: lane covers d-row r4 (of 16 per issue), key-chunk c4, with
  // chunk XOR-swizzled by (d&3). Source is 16B contiguous in Vt[d][s].
  const int r4 = lane >> 2, c4 = lane & 3;
  const u16* vsrc =
      Vtg + hb + (size_t)r4 * SS + kh * 32 + ((c4 ^ (r4 & 3)) * 8);

  // Q B-frags (loop-invariant), direct from global
  bf16x8 qf[2][2];
#pragma unroll
  for (int nb = 0; nb < 2; ++nb)
#pragma unroll
    for (int ch = 0; ch < 2; ++ch)
      qf[nb][ch] = *(const bf16x8*)&Qg[hb +
                                       (size_t)(qt * 64 + qh * 32 + nb * 16 +
                                                l15) *
                                           HDD +
                                       ch * 32 + quad * 8];

  // K A-frags direct from global: row = t*64 + kh*32 + kmb*16 + l15
  const u16* kbase = Kg + hb + (size_t)(kh * 32 + l15) * HDD + quad * 8;
  bf16x8 kf[2][2];
#pragma unroll
  for (int kmb = 0; kmb < 2; ++kmb)
#pragma unroll
    for (int ch = 0; ch < 2; ++ch)
      kf[kmb][ch] = *(const bf16x8*)&kbase[(size_t)(kmb * 16) * HDD + ch * 32];

  // stage V tile 0
#pragma unroll
  for (int u = 0; u < 4; ++u)
    gload_lds16(vsrc + (size_t)(u * 16) * SS, vbuf0 + u * 512);

  float l_acc[2] = {0.f, 0.f};
  floatx4 o[4][2];
#pragma unroll
  for (int dmb = 0; dmb < 4; ++dmb)
#pragma unroll
    for (int nb = 0; nb < 2; ++nb) o[dmb][nb] = (floatx4){0.f, 0.f, 0.f, 0.f};

  const int sub = (quad & 1) * 4;
  const int sx = l15 & 3;
  const int vc0 = ((quad >> 1) ^ sx) * 8 + sub;
  const int vc1 = (((quad >> 1) + 2) ^ sx) * 8 + sub;

  for (int t = 0; t < SS / 64; ++t) {
    // own V(t) lds-writes + K(t) reg loads were issued a full tile ago
    __builtin_amdgcn_s_waitcnt(0);
    const u16* vb = (t & 1) ? vbuf1 : vbuf0;

    // V A-frags (permuted layout): 2 conflict-free b64 per dmb
    bf16x8 au[4];
#pragma unroll
    for (int dmb = 0; dmb < 4; ++dmb) {
      int rb = (dmb * 16 + l15) * 32;
      union { bf16x8 v; uint2 d2[2]; } c;
      c.d2[0] = *(const uint2*)&vb[rb + vc0];
      c.d2[1] = *(const uint2*)&vb[rb + vc1];
      au[dmb] = c.v;
    }

    // prefetch t+1 (V -> other LDS buffer; K -> registers)
    const int tn = (t + 1 < SS / 64) ? t + 1 : t;
    {
      u16* vd = (t & 1) ? vbuf0 : vbuf1;
#pragma unroll
      for (int u = 0; u < 4; ++u)
        gload_lds16(vsrc + (size_t)(u * 16) * SS + tn * 64, vd + u * 512);
    }
    bf16x8 kn[2][2];
#pragma unroll
    for (int kmb = 0; kmb < 2; ++kmb)
#pragma unroll
      for (int ch = 0; ch < 2; ++ch)
        kn[kmb][ch] = *(const bf16x8*)&kbase[(size_t)(tn * 64 + kmb * 16) *
                                                 HDD +
                                             ch * 32];

    // S^T quadrant: keys kmb*16+quad*4+r, qrows nb*16+l15
    floatx4 st[2][2];
#pragma unroll
    for (int kmb = 0; kmb < 2; ++kmb)
#pragma unroll
      for (int nb = 0; nb < 2; ++nb) {
        floatx4 z = (floatx4){0.f, 0.f, 0.f, 0.f};
        z = __builtin_amdgcn_mfma_f32_16x16x32_bf16(kf[kmb][0], qf[nb][0], z,
                                                    0, 0, 0);
        z = __builtin_amdgcn_mfma_f32_16x16x32_bf16(kf[kmb][1], qf[nb][1], z,
                                                    0, 0, 0);
        st[kmb][nb] = z;
      }

    // exp2 + pack P into permuted MFMA-B layout (in-register)
    bf16x8 bp[2];
#pragma unroll
    for (int nb = 0; nb < 2; ++nb) {
      float p00 = exp2f(st[0][nb][0]), p01 = exp2f(st[0][nb][1]);
      float p02 = exp2f(st[0][nb][2]), p03 = exp2f(st[0][nb][3]);
      float p10 = exp2f(st[1][nb][0]), p11 = exp2f(st[1][nb][1]);
      float p12 = exp2f(st[1][nb][2]), p13 = exp2f(st[1][nb][3]);
      l_acc[nb] += ((p00 + p01) + (p02 + p03)) + ((p10 + p11) + (p12 + p13));
      union { bf16x8 v; unsigned u[4]; } pu;
      pu.u[0] = pk_bf16(p00, p01);
      pu.u[1] = pk_bf16(p02, p03);
      pu.u[2] = pk_bf16(p10, p11);
      pu.u[3] = pk_bf16(p12, p13);
      bp[nb] = pu.v;
    }

    // O^T += V^T(perm) · P(perm)
#pragma unroll
    for (int dmb = 0; dmb < 4; ++dmb)
#pragma unroll
      for (int nb = 0; nb < 2; ++nb)
        o[dmb][nb] = __builtin_amdgcn_mfma_f32_16x16x32_bf16(
            au[dmb], bp[nb], o[dmb][nb], 0, 0, 0);

    // rotate K frags
#pragma unroll
    for (int kmb = 0; kmb < 2; ++kmb)
#pragma unroll
      for (int ch = 0; ch < 2; ++ch) kf[kmb][ch] = kn[kmb][ch];
  }

  // ---- epilogue: combine key-halves (only barriers in the kernel) ----
  __syncthreads();  // all waves done with V buffers; safe to overlay
  float* const lpart = (float*)smem;        // [4][32]
  float* const Opart = (float*)smem + 128;  // [2][32][68]

#pragma unroll
  for (int nb = 0; nb < 2; ++nb) {
    l_acc[nb] += __shfl_xor(l_acc[nb], 16);
    l_acc[nb] += __shfl_xor(l_acc[nb], 32);
  }
  if (quad == 0) {
    lpart[wv * 32 + l15] = l_acc[0];
    lpart[wv * 32 + 16 + l15] = l_acc[1];
  }
  if (kh == 1) {
    float* dst = Opart + qh * (32 * 68);
#pragma unroll
    for (int nb = 0; nb < 2; ++nb)
#pragma unroll
      for (int dmb = 0; dmb < 4; ++dmb)
        *(floatx4*)&dst[(nb * 16 + l15) * 68 + dmb * 16 + quad * 4] =
            o[dmb][nb];
  }
  __syncthreads();
  if (kh == 0) {
    const int b = bh >> 4, h = bh & 15;
    const float* src = Opart + qh * (32 * 68);
    float inv[2];
#pragma unroll
    for (int nb = 0; nb < 2; ++nb)
      inv[nb] = 1.f / (lpart[wv * 32 + nb * 16 + l15] +
                       lpart[(wv + 2) * 32 + nb * 16 + l15]);
#pragma unroll
    for (int nb = 0; nb < 2; ++nb) {
      int s = qt * 64 + qh * 32 + nb * 16 + l15;
#pragma unroll
      for (int dmb = 0; dmb < 4; ++dmb) {
        floatx4 part =
            *(const floatx4*)&src[(nb * 16 + l15) * 68 + dmb * 16 + quad * 4];
        floatx4 tot = (o[dmb][nb] + part) * inv[nb];
        uint2 w2;
        w2.x = pk_bf16(tot[0], tot[1]);
        w2.y = pk_bf16(tot[2], tot[3]);
        *(uint2*)&A[((size_t)(b * SS + s) * HH) + h * HDD + dmb * 16 +
                    quad * 4] = w2;
      }
    }
  }
}

// ---------------------------------------------------------------------------
extern "C" void kernel_launch(void* const* d_in, const int* in_sizes, int n_in,
                              void* d_out, int out_size, void* d_ws,
                              size_t ws_size, hipStream_t stream) {
  const float* hs = (const float*)d_in[0];
  const int* pos = (const int*)d_in[1];
  const float* Wq = (const float*)d_in[2];
  const float* bq = (const float*)d_in[3];
  const float* Wk = (const float*)d_in[4];
  const float* bk = (const float*)d_in[5];
  const float* Wv = (const float*)d_in[6];
  const float* bv = (const float*)d_in[7];
  const float* Wo = (const float*)d_in[8];
  float* out = (float*)d_out;

  u16* hs_b = (u16*)d_ws;      // 4M
  u16* wq_b = hs_b + 4194304;  // 1M each
  u16* wk_b = wq_b + 1048576;
  u16* wv_b = wk_b + 1048576;
  u16* wo_b = wv_b + 1048576;
  u16* Qb = wo_b + 1048576;    // 4M each
  u16* Kb = Qb + 4194304;
  u16* Vtb = Kb + 4194304;     // transposed V [bh][d][s]
  u16* Ab = Vtb + 4194304;
  float2* tab = (float2*)(Ab + 4194304);  // [2048][32] cos/sin

  hipLaunchKernelGGL(convert_bf, dim3(8448), dim3(256), 0, stream, hs, Wq, Wk,
                     Wv, Wo, pos, hs_b, wq_b, wk_b, wv_b, wo_b, tab);
  hipLaunchKernelGGL(mfma_gemm_qkv, dim3(24, 32), dim3(256), 0, stream, hs_b,
                     wq_b, wk_b, wv_b, bq, bk, bv, tab, Qb, Kb, Vtb);
  hipLaunchKernelGGL(attn_mfma, dim3(32, 32), dim3(256), 0, stream, Qb, Kb,
                     Vtb, Ab);
  hipLaunchKernelGGL(gemm_out, dim3(16, 32), dim3(256), 0, stream, Ab, wo_b,
                     out);
}

// Round 8
// 241.383 us; speedup vs baseline: 1.0003x; 1.0003x over previous
//
#include <hip/hip_runtime.h>
#include <hip/hip_bf16.h>
#include <math.h>

#define SS 2048
#define HH 1024
#define NHH 16
#define HDD 64
#define BH 32
#define MM 4096

typedef unsigned short u16;
using bf16x8 = __attribute__((ext_vector_type(8))) short;
using floatx4 = __attribute__((ext_vector_type(4))) float;

__device__ __forceinline__ u16 f2bf(float f) {
  unsigned u = __float_as_uint(f);
  u += 0x7fffu + ((u >> 16) & 1u);
  return (u16)(u >> 16);
}
__device__ __forceinline__ unsigned pk_bf16(float a, float b) {
  union { __hip_bfloat162 h2; unsigned u; } c;
  c.h2 = __float22bfloat162_rn(float2{a, b});
  return c.u;
}
__device__ __forceinline__ void gload_lds16(const u16* g, u16* l) {
  __builtin_amdgcn_global_load_lds(
      (const __attribute__((address_space(1))) void*)g,
      (__attribute__((address_space(3))) void*)l, 16, 0, 0);
}

// ---------------------------------------------------------------------------
// fp32 -> bf16 conversion (hs + 4 weights) + RoPE cos/sin table.
// ---------------------------------------------------------------------------
__global__ __launch_bounds__(256) void convert_bf(
    const float* __restrict__ hs, const float* __restrict__ wq,
    const float* __restrict__ wk, const float* __restrict__ wv,
    const float* __restrict__ wo, const int* __restrict__ pos,
    u16* __restrict__ hs_b, u16* __restrict__ wq_b, u16* __restrict__ wk_b,
    u16* __restrict__ wv_b, u16* __restrict__ wo_b,
    float2* __restrict__ tab) {
  int g = blockIdx.x * 256 + threadIdx.x;
  if (g < 2097152) {
    const float* src;
    u16* dst;
    int off;
    if (g < 1048576) {
      src = hs; dst = hs_b; off = g;
    } else {
      int t = g - 1048576;
      int w = t >> 18;
      off = t & 262143;
      src = (w == 0) ? wq : (w == 1) ? wk : (w == 2) ? wv : wo;
      dst = (w == 0) ? wq_b : (w == 1) ? wk_b : (w == 2) ? wv_b : wo_b;
    }
    float4 v = ((const float4*)src)[off];
    ushort4 o = make_ushort4(f2bf(v.x), f2bf(v.y), f2bf(v.z), f2bf(v.w));
    ((ushort4*)dst)[off] = o;
  } else {
    int idx = g - 2097152;  // 0..65535
    int s = idx >> 5, j = idx & 31;
    float p = (float)pos[s];
    const float c0 = 13.287712379549449f / 32.0f;  // log2(10000)/32
    float f = p * exp2f(-(float)j * c0);
    float sn, cs;
    sincosf(f, &sn, &cs);
    tab[idx] = float2{cs, sn};
  }
}

// ---------------------------------------------------------------------------
// QKV MFMA GEMM: 128x128 tile, BK=32, global_load_lds w16, XOR swizzle.
// grid.x spans Wq|Wk|Wv; Q/K get table RoPE in the epilogue (Q pre-scaled by
// (1/sqrt(HD))*log2e), bf16 head-major out; V written transposed Vt[bh][d][s].
// ---------------------------------------------------------------------------
__global__ __launch_bounds__(256) void mfma_gemm_qkv(
    const u16* __restrict__ X, const u16* __restrict__ W0,
    const u16* __restrict__ W1, const u16* __restrict__ W2,
    const float* __restrict__ b0, const float* __restrict__ b1,
    const float* __restrict__ b2, const float2* __restrict__ tab,
    u16* __restrict__ O0, u16* __restrict__ O1, u16* __restrict__ O2) {
  __shared__ __align__(16) u16 As[128 * 32];
  __shared__ __align__(16) u16 Bs[128 * 32];
  const int tid = threadIdx.x;
  const int lane = tid & 63;
  const int wvu = __builtin_amdgcn_readfirstlane(tid >> 6);
  const int l15 = lane & 15;
  const int quad = lane >> 4;
  const int wm = wvu >> 1, wn = wvu & 1;
  const int m0 = blockIdx.y * 128;
  const int n0g = blockIdx.x * 128;
  const int lr = lane >> 2;
  const int lc = lane & 3;

  int wsel = n0g >> 10;
  int n0 = n0g & 1023;
  const u16* Wsel = (wsel == 1) ? W1 : (wsel == 2) ? W2 : W0;
  const float* bsel = (wsel == 1) ? b1 : (wsel == 2) ? b2 : b0;
  u16* Osel = (wsel == 1) ? O1 : (wsel == 2) ? O2 : O0;

  floatx4 acc[4][4];
#pragma unroll
  for (int i = 0; i < 4; ++i)
#pragma unroll
    for (int j = 0; j < 4; ++j) acc[i][j] = (floatx4){0.f, 0.f, 0.f, 0.f};

  const int scol = (lc ^ ((lr >> 1) & 3)) * 8;
  const int fsw = ((l15 >> 1) & 3);

  for (int k0 = 0; k0 < HH; k0 += 32) {
#pragma unroll
    for (int u = 0; u < 2; ++u) {
      int r = u * 64 + wvu * 16 + lr;
      gload_lds16(&X[(size_t)(m0 + r) * HH + k0 + scol],
                  &As[(u * 64 + wvu * 16) * 32]);
      gload_lds16(&Wsel[(size_t)(n0 + r) * HH + k0 + scol],
                  &Bs[(u * 64 + wvu * 16) * 32]);
    }
    __syncthreads();
    bf16x8 af[4], bfr[4];
#pragma unroll
    for (int mb = 0; mb < 4; ++mb)
      af[mb] = *(const bf16x8*)&As[(wm * 64 + mb * 16 + l15) * 32 +
                                   ((quad ^ fsw) * 8)];
#pragma unroll
    for (int nb = 0; nb < 4; ++nb)
      bfr[nb] = *(const bf16x8*)&Bs[(wn * 64 + nb * 16 + l15) * 32 +
                                    ((quad ^ fsw) * 8)];
#pragma unroll
    for (int mb = 0; mb < 4; ++mb)
#pragma unroll
      for (int nb = 0; nb < 4; ++nb)
        acc[mb][nb] = __builtin_amdgcn_mfma_f32_16x16x32_bf16(
            af[mb], bfr[nb], acc[mb][nb], 0, 0, 0);
    __syncthreads();
  }

  if (wsel < 2) {
    const float qs = (wsel == 0) ? 0.125f * 1.44269504088896f : 1.0f;
    const int colb = n0 + wn * 64;
    const int h = colb >> 6;
    const float bias0 = bsel[colb + l15];
    const float bias1 = bsel[colb + 16 + l15];
    const float bias2 = bsel[colb + 32 + l15];
    const float bias3 = bsel[colb + 48 + l15];
#pragma unroll
    for (int mb = 0; mb < 4; ++mb)
#pragma unroll
      for (int r = 0; r < 4; ++r) {
        int m = m0 + wm * 64 + mb * 16 + quad * 4 + r;
        int b = m >> 11, s = m & (SS - 1);
        float2 t0 = tab[s * 32 + l15];
        float2 t1 = tab[s * 32 + 16 + l15];
        size_t obase = ((size_t)(b * NHH + h) * SS + s) * HDD;
        float x1 = acc[mb][0][r] + bias0;
        float x2 = acc[mb][2][r] + bias2;
        Osel[obase + l15] = f2bf((x1 * t0.x - x2 * t0.y) * qs);
        Osel[obase + 32 + l15] = f2bf((x2 * t0.x + x1 * t0.y) * qs);
        float y1 = acc[mb][1][r] + bias1;
        float y2 = acc[mb][3][r] + bias3;
        Osel[obase + 16 + l15] = f2bf((y1 * t1.x - y2 * t1.y) * qs);
        Osel[obase + 48 + l15] = f2bf((y2 * t1.x + y1 * t1.y) * qs);
      }
  } else {
#pragma unroll
    for (int nb = 0; nb < 4; ++nb) {
      int col = n0 + wn * 64 + nb * 16 + l15;
      int h = col >> 6, d = col & 63;
      float bias = bsel[col];
#pragma unroll
      for (int mb = 0; mb < 4; ++mb) {
        int m = m0 + wm * 64 + mb * 16 + quad * 4;
        int b = m >> 11, s = m & (SS - 1);
        uint2 w2;
        w2.x = pk_bf16(acc[mb][nb][0] + bias, acc[mb][nb][1] + bias);
        w2.y = pk_bf16(acc[mb][nb][2] + bias, acc[mb][nb][3] + bias);
        *(uint2*)&Osel[((size_t)((b * NHH + h) * HDD + d)) * SS + s] = w2;
      }
    }
  }
}

// ---------------------------------------------------------------------------
// Final projection GEMM: 128(m) x 64(n) tiles -> 512 blocks. fp32 out.
// ---------------------------------------------------------------------------
__global__ __launch_bounds__(256) void gemm_out(const u16* __restrict__ X,
                                                const u16* __restrict__ W,
                                                float* __restrict__ Ofp) {
  __shared__ __align__(16) u16 As[128 * 32];
  __shared__ __align__(16) u16 Bs[64 * 32];
  const int tid = threadIdx.x;
  const int lane = tid & 63;
  const int wvu = __builtin_amdgcn_readfirstlane(tid >> 6);
  const int l15 = lane & 15;
  const int quad = lane >> 4;
  const int wm = wvu >> 1, wn = wvu & 1;
  const int m0 = blockIdx.y * 128;
  const int n0 = blockIdx.x * 64;
  const int lr = lane >> 2;
  const int lc = lane & 3;

  floatx4 acc[4][2];
#pragma unroll
  for (int i = 0; i < 4; ++i)
#pragma unroll
    for (int j = 0; j < 2; ++j) acc[i][j] = (floatx4){0.f, 0.f, 0.f, 0.f};

  const int scol = (lc ^ ((lr >> 1) & 3)) * 8;
  const int fsw = ((l15 >> 1) & 3);

  for (int k0 = 0; k0 < HH; k0 += 32) {
#pragma unroll
    for (int u = 0; u < 2; ++u) {
      int r = u * 64 + wvu * 16 + lr;
      gload_lds16(&X[(size_t)(m0 + r) * HH + k0 + scol],
                  &As[(u * 64 + wvu * 16) * 32]);
    }
    gload_lds16(&W[(size_t)(n0 + wvu * 16 + lr) * HH + k0 + scol],
                &Bs[(wvu * 16) * 32]);
    __syncthreads();
    bf16x8 af[4], bfr[2];
#pragma unroll
    for (int mb = 0; mb < 4; ++mb)
      af[mb] = *(const bf16x8*)&As[(wm * 64 + mb * 16 + l15) * 32 +
                                   ((quad ^ fsw) * 8)];
#pragma unroll
    for (int nb = 0; nb < 2; ++nb)
      bfr[nb] = *(const bf16x8*)&Bs[(wn * 32 + nb * 16 + l15) * 32 +
                                    ((quad ^ fsw) * 8)];
#pragma unroll
    for (int mb = 0; mb < 4; ++mb)
#pragma unroll
      for (int nb = 0; nb < 2; ++nb)
        acc[mb][nb] = __builtin_amdgcn_mfma_f32_16x16x32_bf16(
            af[mb], bfr[nb], acc[mb][nb], 0, 0, 0);
    __syncthreads();
  }

#pragma unroll
  for (int mb = 0; mb < 4; ++mb)
#pragma unroll
    for (int r = 0; r < 4; ++r) {
      int m = m0 + wm * 64 + mb * 16 + quad * 4 + r;
#pragma unroll
      for (int nb = 0; nb < 2; ++nb)
        Ofp[(size_t)m * HH + n0 + wn * 32 + nb * 16 + l15] = acc[mb][nb][r];
    }
}

// ---------------------------------------------------------------------------
// Flash attention, barrier-free K-loop, v2.
// Grid (bh, qt): bh on blockIdx.x so bh ~ XCD (mod 8) -> each XCD L2 holds
// only 4 bh's K/Vt (2 MB) [rounds 4-7 FETCH evidence].
// Wave (kh,qh) owns keys kh*32..+31 x qrows qh*32..+31. Q/K frags direct
// global->register; V^T in wave-private dbuf LDS quadrants via gload_lds.
// Prefetch order K-THEN-V, so the compiler's auto vmcnt(4) before QK^T waits
// only K; the manual vmcnt(0) (0x0F70: lgkm/exp untouched) sits after softmax,
// giving V staging the whole QK+softmax window. No __syncthreads in the loop.
// ---------------------------------------------------------------------------
__global__ __launch_bounds__(256, 4) void attn_mfma(const u16* __restrict__ Qg,
                                                    const u16* __restrict__ Kg,
                                                    const u16* __restrict__ Vtg,
                                                    u16* __restrict__ A) {
  __shared__ __align__(16) u16 smem[16384];  // 32 KB: 2 bufs x 4 waves x 4 KB
  const int tid = threadIdx.x;
  const int lane = tid & 63;
  const int wv = __builtin_amdgcn_readfirstlane(tid >> 6);
  const int l15 = lane & 15, quad = lane >> 4;
  const int bh = blockIdx.x, qt = blockIdx.y;
  const size_t hb = (size_t)bh * SS * HDD;  // Q,K [bh][s][d]; Vt [bh][d][s]
  const int kh = wv >> 1, qh = wv & 1;

  u16* const vbuf0 = smem + wv * 2048;
  u16* const vbuf1 = smem + 8192 + wv * 2048;

  // V staging: lane covers d-row r4, key-chunk c4, chunk XOR by (d&3).
  const int r4 = lane >> 2, c4 = lane & 3;
  const u16* vsrc =
      Vtg + hb + (size_t)r4 * SS + kh * 32 + ((c4 ^ (r4 & 3)) * 8);

  // Q B-frags (loop-invariant), direct from global
  bf16x8 qf[2][2];
#pragma unroll
  for (int nb = 0; nb < 2; ++nb)
#pragma unroll
    for (int ch = 0; ch < 2; ++ch)
      qf[nb][ch] = *(const bf16x8*)&Qg[hb +
                                       (size_t)(qt * 64 + qh * 32 + nb * 16 +
                                                l15) *
                                           HDD +
                                       ch * 32 + quad * 8];

  // K A-frags direct from global (issued BEFORE V tile-0 staging)
  const u16* kbase = Kg + hb + (size_t)(kh * 32 + l15) * HDD + quad * 8;
  bf16x8 kf[2][2];
#pragma unroll
  for (int kmb = 0; kmb < 2; ++kmb)
#pragma unroll
    for (int ch = 0; ch < 2; ++ch)
      kf[kmb][ch] = *(const bf16x8*)&kbase[(size_t)(kmb * 16) * HDD + ch * 32];

  // stage V tile 0 (after K in program order)
#pragma unroll
  for (int u = 0; u < 4; ++u)
    gload_lds16(vsrc + (size_t)(u * 16) * SS, vbuf0 + u * 512);

  float l_acc[2] = {0.f, 0.f};
  floatx4 o[4][2];
#pragma unroll
  for (int dmb = 0; dmb < 4; ++dmb)
#pragma unroll
    for (int nb = 0; nb < 2; ++nb) o[dmb][nb] = (floatx4){0.f, 0.f, 0.f, 0.f};

  const int sub = (quad & 1) * 4;
  const int sx = l15 & 3;
  const int vc0 = ((quad >> 1) ^ sx) * 8 + sub;
  const int vc1 = (((quad >> 1) + 2) ^ sx) * 8 + sub;

  for (int t = 0; t < SS / 64; ++t) {
    // S^T quadrant (compiler auto-waits kf loads: vmcnt(4), V still in flight)
    floatx4 st[2][2];
#pragma unroll
    for (int kmb = 0; kmb < 2; ++kmb)
#pragma unroll
      for (int nb = 0; nb < 2; ++nb) {
        floatx4 z = (floatx4){0.f, 0.f, 0.f, 0.f};
        z = __builtin_amdgcn_mfma_f32_16x16x32_bf16(kf[kmb][0], qf[nb][0], z,
                                                    0, 0, 0);
        z = __builtin_amdgcn_mfma_f32_16x16x32_bf16(kf[kmb][1], qf[nb][1], z,
                                                    0, 0, 0);
        st[kmb][nb] = z;
      }

    // exp2 + pack P into permuted MFMA-B layout (in-register)
    bf16x8 bp[2];
#pragma unroll
    for (int nb = 0; nb < 2; ++nb) {
      float p00 = exp2f(st[0][nb][0]), p01 = exp2f(st[0][nb][1]);
      float p02 = exp2f(st[0][nb][2]), p03 = exp2f(st[0][nb][3]);
      float p10 = exp2f(st[1][nb][0]), p11 = exp2f(st[1][nb][1]);
      float p12 = exp2f(st[1][nb][2]), p13 = exp2f(st[1][nb][3]);
      l_acc[nb] += ((p00 + p01) + (p02 + p03)) + ((p10 + p11) + (p12 + p13));
      union { bf16x8 v; unsigned u[4]; } pu;
      pu.u[0] = pk_bf16(p00, p01);
      pu.u[1] = pk_bf16(p02, p03);
      pu.u[2] = pk_bf16(p10, p11);
      pu.u[3] = pk_bf16(p12, p13);
      bp[nb] = pu.v;
    }

    // drain remaining vm loads (only this wave's V(t) lds-writes) and read V
    __builtin_amdgcn_s_waitcnt(0x0F70);  // vmcnt(0), lgkm/exp untouched
    const u16* vb = (t & 1) ? vbuf1 : vbuf0;
    bf16x8 au[4];
#pragma unroll
    for (int dmb = 0; dmb < 4; ++dmb) {
      int rb = (dmb * 16 + l15) * 32;
      union { bf16x8 v; uint2 d2[2]; } c;
      c.d2[0] = *(const uint2*)&vb[rb + vc0];
      c.d2[1] = *(const uint2*)&vb[rb + vc1];
      au[dmb] = c.v;
    }

    // prefetch t+1: K (registers) FIRST, then V (gload_lds, other buffer)
    const int tn = (t + 1 < SS / 64) ? t + 1 : t;
    bf16x8 kn[2][2];
#pragma unroll
    for (int kmb = 0; kmb < 2; ++kmb)
#pragma unroll
      for (int ch = 0; ch < 2; ++ch)
        kn[kmb][ch] = *(const bf16x8*)&kbase[(size_t)(tn * 64 + kmb * 16) *
                                                 HDD +
                                             ch * 32];
    {
      u16* vd = (t & 1) ? vbuf0 : vbuf1;
#pragma unroll
      for (int u = 0; u < 4; ++u)
        gload_lds16(vsrc + (size_t)(u * 16) * SS + tn * 64, vd + u * 512);
    }

    // O^T += V^T(perm) · P(perm)
#pragma unroll
    for (int dmb = 0; dmb < 4; ++dmb)
#pragma unroll
      for (int nb = 0; nb < 2; ++nb)
        o[dmb][nb] = __builtin_amdgcn_mfma_f32_16x16x32_bf16(
            au[dmb], bp[nb], o[dmb][nb], 0, 0, 0);

    // rotate K frags
#pragma unroll
    for (int kmb = 0; kmb < 2; ++kmb)
#pragma unroll
      for (int ch = 0; ch < 2; ++ch) kf[kmb][ch] = kn[kmb][ch];
  }

  // ---- epilogue: combine key-halves (only barriers in the kernel) ----
  __syncthreads();  // all waves done with V buffers; safe to overlay
  float* const lpart = (float*)smem;        // [4][32]
  float* const Opart = (float*)smem + 128;  // [2][32][68]

#pragma unroll
  for (int nb = 0; nb < 2; ++nb) {
    l_acc[nb] += __shfl_xor(l_acc[nb], 16);
    l_acc[nb] += __shfl_xor(l_acc[nb], 32);
  }
  if (quad == 0) {
    lpart[wv * 32 + l15] = l_acc[0];
    lpart[wv * 32 + 16 + l15] = l_acc[1];
  }
  if (kh == 1) {
    float* dst = Opart + qh * (32 * 68);
#pragma unroll
    for (int nb = 0; nb < 2; ++nb)
#pragma unroll
      for (int dmb = 0; dmb < 4; ++dmb)
        *(floatx4*)&dst[(nb * 16 + l15) * 68 + dmb * 16 + quad * 4] =
            o[dmb][nb];
  }
  __syncthreads();
  if (kh == 0) {
    const int b = bh >> 4, h = bh & 15;
    const float* src = Opart + qh * (32 * 68);
    float inv[2];
#pragma unroll
    for (int nb = 0; nb < 2; ++nb)
      inv[nb] = 1.f / (lpart[wv * 32 + nb * 16 + l15] +
                       lpart[(wv + 2) * 32 + nb * 16 + l15]);
#pragma unroll
    for (int nb = 0; nb < 2; ++nb) {
      int s = qt * 64 + qh * 32 + nb * 16 + l15;
#pragma unroll
      for (int dmb = 0; dmb < 4; ++dmb) {
        floatx4 part =
            *(const floatx4*)&src[(nb * 16 + l15) * 68 + dmb * 16 + quad * 4];
        floatx4 tot = (o[dmb][nb] + part) * inv[nb];
        uint2 w2;
        w2.x = pk_bf16(tot[0], tot[1]);
        w2.y = pk_bf16(tot[2], tot[3]);
        *(uint2*)&A[((size_t)(b * SS + s) * HH) + h * HDD + dmb * 16 +
                    quad * 4] = w2;
      }
    }
  }
}

// ---------------------------------------------------------------------------
extern "C" void kernel_launch(void* const* d_in, const int* in_sizes, int n_in,
                              void* d_out, int out_size, void* d_ws,
                              size_t ws_size, hipStream_t stream) {
  const float* hs = (const float*)d_in[0];
  const int* pos = (const int*)d_in[1];
  const float* Wq = (const float*)d_in[2];
  const float* bq = (const float*)d_in[3];
  const float* Wk = (const float*)d_in[4];
  const float* bk = (const float*)d_in[5];
  const float* Wv = (const float*)d_in[6];
  const float* bv = (const float*)d_in[7];
  const float* Wo = (const float*)d_in[8];
  float* out = (float*)d_out;

  u16* hs_b = (u16*)d_ws;      // 4M
  u16* wq_b = hs_b + 4194304;  // 1M each
  u16* wk_b = wq_b + 1048576;
  u16* wv_b = wk_b + 1048576;
  u16* wo_b = wv_b + 1048576;
  u16* Qb = wo_b + 1048576;    // 4M each
  u16* Kb = Qb + 4194304;
  u16* Vtb = Kb + 4194304;     // transposed V [bh][d][s]
  u16* Ab = Vtb + 4194304;
  float2* tab = (float2*)(Ab + 4194304);  // [2048][32] cos/sin

  hipLaunchKernelGGL(convert_bf, dim3(8448), dim3(256), 0, stream, hs, Wq, Wk,
                     Wv, Wo, pos, hs_b, wq_b, wk_b, wv_b, wo_b, tab);
  hipLaunchKernelGGL(mfma_gemm_qkv, dim3(24, 32), dim3(256), 0, stream, hs_b,
                     wq_b, wk_b, wv_b, bq, bk, bv, tab, Qb, Kb, Vtb);
  hipLaunchKernelGGL(attn_mfma, dim3(32, 32), dim3(256), 0, stream, Qb, Kb,
                     Vtb, Ab);
  hipLaunchKernelGGL(gemm_out, dim3(16, 32), dim3(256), 0, stream, Ab, wo_b,
                     out);
}